// Round 9
// baseline (128.804 us; speedup 1.0000x reference)
//
#include <hip/hip_runtime.h>
#include <math.h>

#define HW       262144
#define TOTSTEPS (HW / 32)
#define MROWS    100
#define NCOLS    50
#define OUTSZ    (MROWS * NCOLS)

typedef __attribute__((ext_vector_type(8))) _Float16 f16x8;
typedef __attribute__((ext_vector_type(2))) __fp16   fp16x2;   // cvt_pkrtz return type
typedef __attribute__((ext_vector_type(4))) float    f32x4;

// LDS buffer: padded rows of 144 B (128 data + 16 pad).
//   A rows 0..99  -> bytes [0, 14400)
//   B rows 0..49  -> bytes [14400, 21600)
//   pad slots     -> bytes [21600, 24576)   (186 x 16 B, exact fit)
// 24576 B per buffer, double-buffered (49152 B total).
#define ABYTES   14400
#define BUFBYTES 24576

// f16 two-term split: hi = RTZ_f16(x), lo = RTZ_f16(x - hi).
__device__ __forceinline__ void split_f16(const float4& v0, const float4& v1,
                                          f16x8& hi, f16x8& lo) {
  float xs[8] = {v0.x, v0.y, v0.z, v0.w, v1.x, v1.y, v1.z, v1.w};
  union { fp16x2 p[4]; f16x8 v; } H, L;
#pragma unroll
  for (int j = 0; j < 4; ++j) {
    H.p[j] = __builtin_amdgcn_cvt_pkrtz(xs[2 * j], xs[2 * j + 1]);
    float l0 = xs[2 * j]     - (float)H.p[j][0];
    float l1 = xs[2 * j + 1] - (float)H.p[j][1];
    L.p[j] = __builtin_amdgcn_cvt_pkrtz(l0, l1);
  }
  hi = H.v; lo = L.v;
}

// ---------------------------------------------------------------------------
// Phase 1: split-K GEMM, 768 blocks (3/CU), 4 waves (2x2 grid), BK=32 fp32.
// REGISTER-staged (T14): global_load_dwordx4 -> regs -> ds_write_b128.
// ALL staging slots unconditional (tail slots -> LDS pad region) so the
// staging arrays promote to SSA registers (R8's `if(ok)` caused scratch
// spill: VGPR=68, WRITE_SIZE=188MB).
// ---------------------------------------------------------------------------
__global__ __launch_bounds__(256, 3) void dm_phase1(
    const float* __restrict__ pred, const float* __restrict__ gt,
    float* __restrict__ partial, int nblk) {
  __shared__ unsigned char smem[2 * BUFBYTES];

  const int b    = blockIdx.x;
  const int tid  = threadIdx.x;
  const int lane = tid & 63;
  const int wid  = tid >> 6;
  const int wi = wid >> 1, wj = wid & 1;
  const int g = lane >> 4, r = lane & 15;

  const int k0s = (int)(((long)b * TOTSTEPS) / nblk);
  const int k1s = (int)(((long)(b + 1) * TOTSTEPS) / nblk);
  const int nst = k1s - k0s;

  // per-thread staging slots: slot = it*256 + tid (0..1535), all live.
  const float* srcp[6];
  int ldso[6];
#pragma unroll
  for (int it = 0; it < 6; ++it) {
    int s = it * 256 + tid;
    int row, off;
    const float* base;
    int lbase;
    if (s < 900)       { row = s / 9;  off = (s - row * 9) * 16;  base = pred; lbase = 0; }
    else if (s < 1350) { int s2 = s - 900;
                         row = s2 / 9; off = (s2 - row * 9) * 16; base = gt;   lbase = ABYTES; }
    else               { row = 0;      off = (s - 1350) * 16;     base = pred; lbase = 21600 - 0 * 144; 
                         // pad slots: ldso = 21600 + (s-1350)*16 via row=0,off below
                       }
    if (s < 1350) {
      int soff = off > 112 ? 112 : off;     // 9th slot: dup of bytes 112..127
      srcp[it] = base + (size_t)row * HW + (soff >> 2);
      ldso[it] = lbase + row * 144 + soff;
    } else {
      srcp[it] = pred + ((s - 1350) & 127); // harmless valid address
      ldso[it] = 21600 + (s - 1350) * 16;   // exact-fit pad region
    }
  }

  auto LOADREG = [&](float4 (&rg)[6], int kf) {
#pragma unroll
    for (int it = 0; it < 6; ++it)
      rg[it] = *(const float4*)(srcp[it] + kf);
  };
  auto WRITE = [&](unsigned char* bufb, float4 (&rg)[6]) {
#pragma unroll
    for (int it = 0; it < 6; ++it)
      *(float4*)(bufb + ldso[it]) = rg[it];
  };

  f32x4 acc[4][2] = {};

  auto COMPUTE = [&](const unsigned char* bufb) {
    f16x8 bh[2], bl[2];
#pragma unroll
    for (int nf = 0; nf < 2; ++nf) {
      int R = wj * 32 + nf * 16 + r;
      if (R > NCOLS - 1) R = NCOLS - 1;    // clamped cols -> outputs discarded
      const unsigned char* rowb = bufb + ABYTES + R * 144;
      float4 v0 = *(const float4*)(rowb + 32 * g);
      float4 v1 = *(const float4*)(rowb + 32 * g + 16);
      split_f16(v0, v1, bh[nf], bl[nf]);
    }
#pragma unroll
    for (int mf = 0; mf < 4; ++mf) {
      if (wi == 0 || mf < 3) {             // rows 112..127 don't exist
        int R = wi * 64 + mf * 16 + r;
        if (R > MROWS - 1) R = MROWS - 1;  // clamped rows -> outputs discarded
        const unsigned char* rowb = bufb + R * 144;
        float4 v0 = *(const float4*)(rowb + 32 * g);
        float4 v1 = *(const float4*)(rowb + 32 * g + 16);
        f16x8 ah, al;
        split_f16(v0, v1, ah, al);
#pragma unroll
        for (int nf = 0; nf < 2; ++nf) {
          acc[mf][nf] = __builtin_amdgcn_mfma_f32_16x16x32_f16(ah, bh[nf], acc[mf][nf], 0, 0, 0);
          acc[mf][nf] = __builtin_amdgcn_mfma_f32_16x16x32_f16(al, bh[nf], acc[mf][nf], 0, 0, 0);
          acc[mf][nf] = __builtin_amdgcn_mfma_f32_16x16x32_f16(ah, bl[nf], acc[mf][nf], 0, 0, 0);
        }
      }
    }
  };

  unsigned char* buf0 = smem;
  unsigned char* buf1 = smem + BUFBYTES;

  // prologue: stage 0 -> buf0; stage 1 -> regs (in flight)
  float4 ra[6], rb[6];
  LOADREG(ra, k0s << 5);
  if (nst > 1) LOADREG(rb, (k0s + 1) << 5);
  WRITE(buf0, ra);                          // waits only on ra's loads
  __syncthreads();

  for (int s = 0; s < nst; s += 2) {
    // even half: compute stage s from buf0; rb holds stage s+1
    if (s + 1 < nst) {
      WRITE(buf1, rb);
      if (s + 2 < nst) LOADREG(ra, (k0s + s + 2) << 5);
    }
    COMPUTE(buf0);
    __syncthreads();
    if (s + 1 >= nst) break;
    // odd half: compute stage s+1 from buf1; ra holds stage s+2
    if (s + 2 < nst) {
      WRITE(buf0, ra);
      if (s + 3 < nst) LOADREG(rb, (k0s + s + 3) << 5);
    }
    COMPUTE(buf1);
    __syncthreads();
  }

  // epilogue: C/D layout col = lane&15, row = 4*(lane>>4)+reg
#pragma unroll
  for (int mf = 0; mf < 4; ++mf) {
#pragma unroll
    for (int nf = 0; nf < 2; ++nf) {
#pragma unroll
      for (int qq = 0; qq < 4; ++qq) {
        int row = wi * 64 + mf * 16 + g * 4 + qq;
        int col = wj * 32 + nf * 16 + r;
        if (row < MROWS && col < NCOLS)
          partial[(size_t)b * OUTSZ + row * NCOLS + col] = acc[mf][nf][qq];
      }
    }
  }
}

// ---------------------------------------------------------------------------
// Phase 2a: sum partials over blocks. One wave per 4 consecutive p; all NB/64
// float4 loads issued independently, reduce in double.
// ---------------------------------------------------------------------------
template <int NB>
__global__ void dm_reduce(const float* __restrict__ partial,
                          double* __restrict__ la0) {
  const int tid = threadIdx.x, wid = tid >> 6, lane = tid & 63;
  const int pbase = blockIdx.x * 16 + wid * 4;
  if (pbase >= OUTSZ) return;
  constexpr int IT = NB / 64;
  float4 v[IT];
#pragma unroll
  for (int i = 0; i < IT; ++i)
    v[i] = *(const float4*)(partial + (size_t)(lane + 64 * i) * OUTSZ + pbase);
  double d0 = 0, d1 = 0, d2 = 0, d3 = 0;
#pragma unroll
  for (int i = 0; i < IT; ++i) {
    d0 += (double)v[i].x; d1 += (double)v[i].y;
    d2 += (double)v[i].z; d3 += (double)v[i].w;
  }
#pragma unroll
  for (int off = 32; off; off >>= 1) {
    d0 += __shfl_xor(d0, off);
    d1 += __shfl_xor(d1, off);
    d2 += __shfl_xor(d2, off);
    d3 += __shfl_xor(d3, off);
  }
  if (lane == 0) {
    la0[pbase + 0] = (d0 - 1.0) * 10.0;     // -(1-dot)/0.1
    la0[pbase + 1] = (d1 - 1.0) * 10.0;
    la0[pbase + 2] = (d2 - 1.0) * 10.0;
    la0[pbase + 3] = (d3 - 1.0) * 10.0;
  }
}

// ---------------------------------------------------------------------------
// Phase 2b: Sinkhorn via dual potentials (double), fast __expf on f32 deltas.
// ---------------------------------------------------------------------------
__global__ __launch_bounds__(256) void dm_sinkhorn(const double* __restrict__ la_in,
                                                   float* __restrict__ out) {
  __shared__ double la[OUTSZ];
  __shared__ double rp[MROWS];
  __shared__ double cp[NCOLS];
  const int t = threadIdx.x;
  for (int p = t; p < OUTSZ; p += 256) la[p] = la_in[p];
  if (t < NCOLS) cp[t] = 0.0;
  __syncthreads();
  for (int it = 0; it < 5; ++it) {
    if (t < 2 * MROWS) {                    // rows: 2 lanes per row
      int row = t >> 1, sl = t & 1;
      double m = -1e300;
      for (int j = sl; j < NCOLS; j += 2) m = fmax(m, la[row * NCOLS + j] - cp[j]);
      float s = 0.f;
      for (int j = sl; j < NCOLS; j += 2)
        s += __expf((float)(la[row * NCOLS + j] - cp[j] - m));
      double mo = __shfl_xor(m, 1); float so = __shfl_xor(s, 1);
      double mn = fmax(m, mo);
      s = s * __expf((float)(m - mn)) + so * __expf((float)(mo - mn));
      if (sl == 0) rp[row] = mn + (double)__logf(s);
    }
    __syncthreads();
    if (t < 4 * NCOLS) {                    // cols: 4 lanes per col
      int col = t >> 2, sl = t & 3;
      double m = -1e300;
      for (int i = sl; i < MROWS; i += 4) m = fmax(m, la[i * NCOLS + col] - rp[i]);
      float s = 0.f;
      for (int i = sl; i < MROWS; i += 4)
        s += __expf((float)(la[i * NCOLS + col] - rp[i] - m));
#pragma unroll
      for (int off = 1; off < 4; off <<= 1) {
        double mo = __shfl_xor(m, off); float so = __shfl_xor(s, off);
        double mn = fmax(m, mo);
        s = s * __expf((float)(m - mn)) + so * __expf((float)(mo - mn));
        m = mn;
      }
      if (sl == 0) cp[col] = m + (double)__logf(s);
    }
    __syncthreads();
  }
  for (int p = t; p < OUTSZ; p += 256)
    out[p] = __expf((float)(la[p] - rp[p / NCOLS] - cp[p % NCOLS]));
}

extern "C" void kernel_launch(void* const* d_in, const int* in_sizes, int n_in,
                              void* d_out, int out_size, void* d_ws, size_t ws_size,
                              hipStream_t stream) {
  const float* pred = (const float*)d_in[0];   // [1,100,512,512] fp32
  const float* gt   = (const float*)d_in[1];   // [50,512,512]    fp32
  float* out = (float*)d_out;                  // [1,100,50]      fp32

  auto fits = [&](int nb) {
    return ((size_t)nb * OUTSZ * sizeof(float) + OUTSZ * sizeof(double)) <= ws_size;
  };
  int nblk = fits(768) ? 768 : (fits(512) ? 512 : 256);

  float*  partial = (float*)d_ws;
  double* la0 = (double*)((char*)d_ws + (size_t)nblk * OUTSZ * sizeof(float));

  dm_phase1<<<nblk, 256, 0, stream>>>(pred, gt, partial, nblk);
  if (nblk == 768)      dm_reduce<768><<<(OUTSZ + 15) / 16, 256, 0, stream>>>(partial, la0);
  else if (nblk == 512) dm_reduce<512><<<(OUTSZ + 15) / 16, 256, 0, stream>>>(partial, la0);
  else                  dm_reduce<256><<<(OUTSZ + 15) / 16, 256, 0, stream>>>(partial, la0);
  dm_sinkhorn<<<1, 256, 0, stream>>>(la0, out);
}

// Round 10
// 76.951 us; speedup vs baseline: 1.6738x; 1.6738x over previous
//
#include <hip/hip_runtime.h>
#include <math.h>

#define HW       262144
#define TOTSTEPS (HW / 32)
#define MROWS    100
#define NCOLS    50
#define OUTSZ    (MROWS * NCOLS)

typedef __attribute__((ext_vector_type(8))) _Float16 f16x8;
typedef __attribute__((ext_vector_type(2))) __fp16   fp16x2;   // cvt_pkrtz return type
typedef __attribute__((ext_vector_type(4))) float    f32x4;

// LDS buffer: padded rows of 144 B (128 data + 16 pad).
//   A rows 0..99  -> bytes [0, 14400)
//   B rows 0..49  -> bytes [14400, 21600)
//   tail slots    -> bytes [21600, 24576)   (186 x 16 B, exact fit)
// 24576 B per buffer, double-buffered (49152 B total).
#define ABYTES   14400
#define BUFBYTES 24576

// slot -> (global src ptr, LDS byte offset). 9 x 16B slots per 128B row
// (9th slot = dup of bytes 112..127; two threads write same LDS addr with
// same data -> benign).
__device__ __forceinline__ void slot_map(int s, const float* pred,
                                         const float* gt,
                                         const float*& sp, int& lo) {
  if (s < 900) {                       // A rows 0..99
    int row = s / 9, off = (s - row * 9) * 16;
    int soff = off > 112 ? 112 : off;
    sp = pred + (size_t)row * HW + (soff >> 2);
    lo = row * 144 + soff;
  } else if (s < 1350) {               // B rows 0..49
    int s2 = s - 900;
    int row = s2 / 9, off = (s2 - row * 9) * 16;
    int soff = off > 112 ? 112 : off;
    sp = gt + (size_t)row * HW + (soff >> 2);
    lo = ABYTES + row * 144 + soff;
  } else {                             // tail slots -> LDS pad region
    sp = pred + ((s - 1350) & 127);
    lo = 21600 + (s - 1350) * 16;
  }
}

// f16 two-term split: hi = RTZ_f16(x), lo = RTZ_f16(x - hi).
__device__ __forceinline__ void split_f16(const float4& v0, const float4& v1,
                                          f16x8& hi, f16x8& lo) {
  float xs[8] = {v0.x, v0.y, v0.z, v0.w, v1.x, v1.y, v1.z, v1.w};
  union { fp16x2 p[4]; f16x8 v; } H, L;
#pragma unroll
  for (int j = 0; j < 4; ++j) {
    H.p[j] = __builtin_amdgcn_cvt_pkrtz(xs[2 * j], xs[2 * j + 1]);
    float l0 = xs[2 * j]     - (float)H.p[j][0];
    float l1 = xs[2 * j + 1] - (float)H.p[j][1];
    L.p[j] = __builtin_amdgcn_cvt_pkrtz(l0, l1);
  }
  hi = H.v; lo = L.v;
}

// ---------------------------------------------------------------------------
// Phase 1: split-K GEMM, 512 blocks (2/CU), 4 waves (2x2 grid), BK=32 fp32.
// REGISTER-staged: global_load_dwordx4 -> named scalar float4s ->
// ds_write_b128. NO arrays, NO array-ref lambda params (R8/R9 lesson: both
// defeated SROA -> 200MB scratch traffic, VGPR=68). launch_bounds (256,2)
// so the ~180-reg working set fits without spill.
// ---------------------------------------------------------------------------
__global__ __launch_bounds__(256, 2) void dm_phase1(
    const float* __restrict__ pred, const float* __restrict__ gt,
    float* __restrict__ partial, int nblk) {
  __shared__ unsigned char smem[2 * BUFBYTES];

  const int b    = blockIdx.x;
  const int tid  = threadIdx.x;
  const int lane = tid & 63;
  const int wid  = tid >> 6;
  const int wi = wid >> 1, wj = wid & 1;
  const int g = lane >> 4, r = lane & 15;

  const int k0s = (int)(((long)b * TOTSTEPS) / nblk);
  const int k1s = (int)(((long)(b + 1) * TOTSTEPS) / nblk);
  const int nst = k1s - k0s;

  const float *sp0, *sp1, *sp2, *sp3, *sp4, *sp5;
  int lo0, lo1, lo2, lo3, lo4, lo5;
  slot_map(        tid, pred, gt, sp0, lo0);
  slot_map( 256  + tid, pred, gt, sp1, lo1);
  slot_map( 512  + tid, pred, gt, sp2, lo2);
  slot_map( 768  + tid, pred, gt, sp3, lo3);
  slot_map(1024  + tid, pred, gt, sp4, lo4);
  slot_map(1280  + tid, pred, gt, sp5, lo5);

  float4 ra0, ra1, ra2, ra3, ra4, ra5;
  float4 rb0, rb1, rb2, rb3, rb4, rb5;

#define LOADA(kf) do { int _k = (kf);                      \
    ra0 = *(const float4*)(sp0 + _k);                      \
    ra1 = *(const float4*)(sp1 + _k);                      \
    ra2 = *(const float4*)(sp2 + _k);                      \
    ra3 = *(const float4*)(sp3 + _k);                      \
    ra4 = *(const float4*)(sp4 + _k);                      \
    ra5 = *(const float4*)(sp5 + _k); } while (0)
#define LOADB(kf) do { int _k = (kf);                      \
    rb0 = *(const float4*)(sp0 + _k);                      \
    rb1 = *(const float4*)(sp1 + _k);                      \
    rb2 = *(const float4*)(sp2 + _k);                      \
    rb3 = *(const float4*)(sp3 + _k);                      \
    rb4 = *(const float4*)(sp4 + _k);                      \
    rb5 = *(const float4*)(sp5 + _k); } while (0)
#define WRA(bufb) do { unsigned char* _b = (bufb);         \
    *(float4*)(_b + lo0) = ra0;                            \
    *(float4*)(_b + lo1) = ra1;                            \
    *(float4*)(_b + lo2) = ra2;                            \
    *(float4*)(_b + lo3) = ra3;                            \
    *(float4*)(_b + lo4) = ra4;                            \
    *(float4*)(_b + lo5) = ra5; } while (0)
#define WRB(bufb) do { unsigned char* _b = (bufb);         \
    *(float4*)(_b + lo0) = rb0;                            \
    *(float4*)(_b + lo1) = rb1;                            \
    *(float4*)(_b + lo2) = rb2;                            \
    *(float4*)(_b + lo3) = rb3;                            \
    *(float4*)(_b + lo4) = rb4;                            \
    *(float4*)(_b + lo5) = rb5; } while (0)

  f32x4 acc[4][2] = {};

  auto COMPUTE = [&](const unsigned char* bufb) {
    f16x8 bh[2], bl[2];
#pragma unroll
    for (int nf = 0; nf < 2; ++nf) {
      int R = wj * 32 + nf * 16 + r;
      if (R > NCOLS - 1) R = NCOLS - 1;    // clamped cols -> outputs discarded
      const unsigned char* rowb = bufb + ABYTES + R * 144;
      float4 v0 = *(const float4*)(rowb + 32 * g);
      float4 v1 = *(const float4*)(rowb + 32 * g + 16);
      split_f16(v0, v1, bh[nf], bl[nf]);
    }
#pragma unroll
    for (int mf = 0; mf < 4; ++mf) {
      if (wi == 0 || mf < 3) {             // rows 112..127 don't exist
        int R = wi * 64 + mf * 16 + r;
        if (R > MROWS - 1) R = MROWS - 1;  // clamped rows -> outputs discarded
        const unsigned char* rowb = bufb + R * 144;
        float4 v0 = *(const float4*)(rowb + 32 * g);
        float4 v1 = *(const float4*)(rowb + 32 * g + 16);
        f16x8 ah, al;
        split_f16(v0, v1, ah, al);
#pragma unroll
        for (int nf = 0; nf < 2; ++nf) {
          acc[mf][nf] = __builtin_amdgcn_mfma_f32_16x16x32_f16(ah, bh[nf], acc[mf][nf], 0, 0, 0);
          acc[mf][nf] = __builtin_amdgcn_mfma_f32_16x16x32_f16(al, bh[nf], acc[mf][nf], 0, 0, 0);
          acc[mf][nf] = __builtin_amdgcn_mfma_f32_16x16x32_f16(ah, bl[nf], acc[mf][nf], 0, 0, 0);
        }
      }
    }
  };

  unsigned char* buf0 = smem;
  unsigned char* buf1 = smem + BUFBYTES;

  // prologue: stage 0 -> buf0; stage 1 -> regs (in flight)
  LOADA(k0s << 5);
  if (nst > 1) LOADB((k0s + 1) << 5);
  WRA(buf0);                               // waits only on ra loads
  __syncthreads();

  for (int s = 0; s < nst; s += 2) {
    // even half: compute stage s from buf0; rb holds stage s+1
    if (s + 1 < nst) {
      WRB(buf1);
      if (s + 2 < nst) LOADA((k0s + s + 2) << 5);
    }
    COMPUTE(buf0);
    __syncthreads();
    if (s + 1 >= nst) break;
    // odd half: compute stage s+1 from buf1; ra holds stage s+2
    if (s + 2 < nst) {
      WRA(buf0);
      if (s + 3 < nst) LOADB((k0s + s + 3) << 5);
    }
    COMPUTE(buf1);
    __syncthreads();
  }

#undef LOADA
#undef LOADB
#undef WRA
#undef WRB

  // epilogue: C/D layout col = lane&15, row = 4*(lane>>4)+reg
#pragma unroll
  for (int mf = 0; mf < 4; ++mf) {
#pragma unroll
    for (int nf = 0; nf < 2; ++nf) {
#pragma unroll
      for (int qq = 0; qq < 4; ++qq) {
        int row = wi * 64 + mf * 16 + g * 4 + qq;
        int col = wj * 32 + nf * 16 + r;
        if (row < MROWS && col < NCOLS)
          partial[(size_t)b * OUTSZ + row * NCOLS + col] = acc[mf][nf][qq];
      }
    }
  }
}

// ---------------------------------------------------------------------------
// Phase 2a: sum partials over blocks. One wave per 4 consecutive p; all NB/64
// float4 loads issued independently, reduce in double.
// ---------------------------------------------------------------------------
template <int NB>
__global__ void dm_reduce(const float* __restrict__ partial,
                          double* __restrict__ la0) {
  const int tid = threadIdx.x, wid = tid >> 6, lane = tid & 63;
  const int pbase = blockIdx.x * 16 + wid * 4;
  if (pbase >= OUTSZ) return;
  constexpr int IT = NB / 64;
  float4 v[IT];
#pragma unroll
  for (int i = 0; i < IT; ++i)
    v[i] = *(const float4*)(partial + (size_t)(lane + 64 * i) * OUTSZ + pbase);
  double d0 = 0, d1 = 0, d2 = 0, d3 = 0;
#pragma unroll
  for (int i = 0; i < IT; ++i) {
    d0 += (double)v[i].x; d1 += (double)v[i].y;
    d2 += (double)v[i].z; d3 += (double)v[i].w;
  }
#pragma unroll
  for (int off = 32; off; off >>= 1) {
    d0 += __shfl_xor(d0, off);
    d1 += __shfl_xor(d1, off);
    d2 += __shfl_xor(d2, off);
    d3 += __shfl_xor(d3, off);
  }
  if (lane == 0) {
    la0[pbase + 0] = (d0 - 1.0) * 10.0;     // -(1-dot)/0.1
    la0[pbase + 1] = (d1 - 1.0) * 10.0;
    la0[pbase + 2] = (d2 - 1.0) * 10.0;
    la0[pbase + 3] = (d3 - 1.0) * 10.0;
  }
}

// ---------------------------------------------------------------------------
// Phase 2b: Sinkhorn via dual potentials (double), fast __expf on f32 deltas.
// ---------------------------------------------------------------------------
__global__ __launch_bounds__(256) void dm_sinkhorn(const double* __restrict__ la_in,
                                                   float* __restrict__ out) {
  __shared__ double la[OUTSZ];
  __shared__ double rp[MROWS];
  __shared__ double cp[NCOLS];
  const int t = threadIdx.x;
  for (int p = t; p < OUTSZ; p += 256) la[p] = la_in[p];
  if (t < NCOLS) cp[t] = 0.0;
  __syncthreads();
  for (int it = 0; it < 5; ++it) {
    if (t < 2 * MROWS) {                    // rows: 2 lanes per row
      int row = t >> 1, sl = t & 1;
      double m = -1e300;
      for (int j = sl; j < NCOLS; j += 2) m = fmax(m, la[row * NCOLS + j] - cp[j]);
      float s = 0.f;
      for (int j = sl; j < NCOLS; j += 2)
        s += __expf((float)(la[row * NCOLS + j] - cp[j] - m));
      double mo = __shfl_xor(m, 1); float so = __shfl_xor(s, 1);
      double mn = fmax(m, mo);
      s = s * __expf((float)(m - mn)) + so * __expf((float)(mo - mn));
      if (sl == 0) rp[row] = mn + (double)__logf(s);
    }
    __syncthreads();
    if (t < 4 * NCOLS) {                    // cols: 4 lanes per col
      int col = t >> 2, sl = t & 3;
      double m = -1e300;
      for (int i = sl; i < MROWS; i += 4) m = fmax(m, la[i * NCOLS + col] - rp[i]);
      float s = 0.f;
      for (int i = sl; i < MROWS; i += 4)
        s += __expf((float)(la[i * NCOLS + col] - rp[i] - m));
#pragma unroll
      for (int off = 1; off < 4; off <<= 1) {
        double mo = __shfl_xor(m, off); float so = __shfl_xor(s, off);
        double mn = fmax(m, mo);
        s = s * __expf((float)(m - mn)) + so * __expf((float)(mo - mn));
        m = mn;
      }
      if (sl == 0) cp[col] = m + (double)__logf(s);
    }
    __syncthreads();
  }
  for (int p = t; p < OUTSZ; p += 256)
    out[p] = __expf((float)(la[p] - rp[p / NCOLS] - cp[p % NCOLS]));
}

extern "C" void kernel_launch(void* const* d_in, const int* in_sizes, int n_in,
                              void* d_out, int out_size, void* d_ws, size_t ws_size,
                              hipStream_t stream) {
  const float* pred = (const float*)d_in[0];   // [1,100,512,512] fp32
  const float* gt   = (const float*)d_in[1];   // [50,512,512]    fp32
  float* out = (float*)d_out;                  // [1,100,50]      fp32

  auto fits = [&](int nb) {
    return ((size_t)nb * OUTSZ * sizeof(float) + OUTSZ * sizeof(double)) <= ws_size;
  };
  int nblk = fits(512) ? 512 : 256;

  float*  partial = (float*)d_ws;
  double* la0 = (double*)((char*)d_ws + (size_t)nblk * OUTSZ * sizeof(float));

  dm_phase1<<<nblk, 256, 0, stream>>>(pred, gt, partial, nblk);
  if (nblk == 512) dm_reduce<512><<<(OUTSZ + 15) / 16, 256, 0, stream>>>(partial, la0);
  else             dm_reduce<256><<<(OUTSZ + 15) / 16, 256, 0, stream>>>(partial, la0);
  dm_sinkhorn<<<1, 256, 0, stream>>>(la0, out);
}